// Round 1
// baseline (322.800 us; speedup 1.0000x reference)
//
#include <hip/hip_runtime.h>
#include <math.h>

#define BB 4
#define NN 8192
#define KNB 16
#define DD 128
#define HH 4
#define DKK 32
#define SS 17            // K+1 (self + neighbors)
#define M_TOT (BB*NN)    // 32768

// ---------------------------------------------------------------------------
// Y[M,128] = act(X[M,128] @ W[128,128] + bias), relu optional.
// Block: 256 threads, 32 rows per block. W staged in LDS in two 64-row halves
// (48 KB total LDS -> 3 blocks/CU). Each thread computes a 4x4 register tile.
// ---------------------------------------------------------------------------
__global__ __launch_bounds__(256) void gemm_bias_kernel(
    const float* __restrict__ X, const float* __restrict__ W,
    const float* __restrict__ bias, float* __restrict__ Y, int relu)
{
    __shared__ float Ws[64 * 128];   // 32 KB
    __shared__ float Xs[32 * 128];   // 16 KB

    const int tid  = threadIdx.x;
    const int row0 = blockIdx.x * 32;

    // Load X tile: 32x128 floats = 1024 float4, 4 per thread, coalesced.
    {
        const float4* Xg  = (const float4*)(X + (size_t)row0 * DD);
        float4*       Xs4 = (float4*)Xs;
        #pragma unroll
        for (int i = 0; i < 4; ++i) Xs4[tid + i * 256] = Xg[tid + i * 256];
    }

    const int tx = tid & 31;   // col group: cols tx*4 .. tx*4+3
    const int ty = tid >> 5;   // row group: rows ty*4 .. ty*4+3

    float acc[4][4];
    #pragma unroll
    for (int i = 0; i < 4; ++i)
        #pragma unroll
        for (int j = 0; j < 4; ++j) acc[i][j] = 0.f;

    for (int kb = 0; kb < 2; ++kb) {
        __syncthreads();   // protect Ws from previous iteration's readers
        // Load W rows [kb*64, kb*64+64): 8192 floats = 2048 float4.
        {
            const float4* Wg  = (const float4*)(W + kb * 64 * DD);
            float4*       Ws4 = (float4*)Ws;
            #pragma unroll
            for (int i = 0; i < 8; ++i) Ws4[tid + i * 256] = Wg[tid + i * 256];
        }
        __syncthreads();

        #pragma unroll 8
        for (int d = 0; d < 64; ++d) {
            float4 bv = ((const float4*)Ws)[d * 32 + tx];
            #pragma unroll
            for (int i = 0; i < 4; ++i) {
                float a = Xs[(ty * 4 + i) * DD + kb * 64 + d];
                acc[i][0] = fmaf(a, bv.x, acc[i][0]);
                acc[i][1] = fmaf(a, bv.y, acc[i][1]);
                acc[i][2] = fmaf(a, bv.z, acc[i][2]);
                acc[i][3] = fmaf(a, bv.w, acc[i][3]);
            }
        }
    }

    float4 bb = ((const float4*)bias)[tx];
    #pragma unroll
    for (int i = 0; i < 4; ++i) {
        float4 o;
        o.x = acc[i][0] + bb.x;
        o.y = acc[i][1] + bb.y;
        o.z = acc[i][2] + bb.z;
        o.w = acc[i][3] + bb.w;
        if (relu) {
            o.x = fmaxf(o.x, 0.f); o.y = fmaxf(o.y, 0.f);
            o.z = fmaxf(o.z, 0.f); o.w = fmaxf(o.w, 0.f);
        }
        ((float4*)(Y + (size_t)(row0 + ty * 4 + i) * DD))[tx] = o;
    }
}

// ---------------------------------------------------------------------------
// Attention: per vertex v, gather kh/vh rows of {self, 16 neighbors} into LDS,
// per-head (H=4, DK=32) scores via shfl-32 reduction, masked softmax over
// s <= valid_len, ctx[t] = sum_s attn * vh. 128 threads per vertex,
// 2 vertices per 256-thread block.
// ---------------------------------------------------------------------------
__global__ __launch_bounds__(256) void attn_kernel(
    const float* __restrict__ Qh, const float* __restrict__ Kh,
    const float* __restrict__ Vh, const int* __restrict__ nbr,
    const int* __restrict__ vlen, float* __restrict__ Ctx)
{
    __shared__ float kh[2][SS][DD];      // 17 KB
    __shared__ float vh[2][SS][DD];      // 17 KB
    __shared__ float sc[2][HH][SS];
    __shared__ int   sidx[2][SS];

    const int tid  = threadIdx.x;
    const int slot = tid >> 7;       // 0 or 1
    const int t    = tid & 127;      // dim index within vertex
    const int v    = blockIdx.x * 2 + slot;
    const int b    = v >> 13;        // v / N

    if (t < SS) {
        int row = (t == 0) ? v : (b * NN + nbr[(size_t)v * KNB + (t - 1)]);
        sidx[slot][t] = row;
    }
    __syncthreads();

    const float qd = Qh[(size_t)v * DD + t];

    #pragma unroll
    for (int s = 0; s < SS; ++s) {
        const int row = sidx[slot][s];
        kh[slot][s][t] = Kh[(size_t)row * DD + t];
        vh[slot][s][t] = Vh[(size_t)row * DD + t];
    }
    __syncthreads();

    const int h = t >> 5;            // head = dim/32

    // scores[h][s] = (qh_h . kh_s_h) / sqrt(32)
    for (int s = 0; s < SS; ++s) {
        float p = qd * kh[slot][s][t];
        p += __shfl_down(p, 16, 32);
        p += __shfl_down(p, 8, 32);
        p += __shfl_down(p, 4, 32);
        p += __shfl_down(p, 2, 32);
        p += __shfl_down(p, 1, 32);
        if ((t & 31) == 0) sc[slot][h][s] = p * 0.17677669529663687f; // 1/sqrt(32)
    }
    __syncthreads();

    // masked softmax, one thread per head
    if (t < HH) {
        const int hh  = t;
        const int len = vlen[v];     // valid positions: s in [0, len]
        float m = -1e30f;
        for (int s = 0; s <= len; ++s) m = fmaxf(m, sc[slot][hh][s]);
        float sum = 0.f;
        for (int s = 0; s < SS; ++s) {
            float x = (s <= len) ? __expf(sc[slot][hh][s] - m) : 0.f;
            sc[slot][hh][s] = x;
            sum += x;
        }
        const float inv = 1.f / sum;
        for (int s = 0; s < SS; ++s) sc[slot][hh][s] *= inv;
    }
    __syncthreads();

    float acc = 0.f;
    #pragma unroll
    for (int s = 0; s < SS; ++s) acc = fmaf(sc[slot][h][s], vh[slot][s][t], acc);
    Ctx[(size_t)v * DD + t] = acc;
}

// ---------------------------------------------------------------------------
extern "C" void kernel_launch(void* const* d_in, const int* in_sizes, int n_in,
                              void* d_out, int out_size, void* d_ws, size_t ws_size,
                              hipStream_t stream)
{
    const float* vf   = (const float*)d_in[0];
    const int*   nbr  = (const int*)  d_in[1];
    const int*   vlen = (const int*)  d_in[2];
    const float* Wq   = (const float*)d_in[3];
    const float* bq   = (const float*)d_in[4];
    const float* Wk   = (const float*)d_in[5];
    const float* bk   = (const float*)d_in[6];
    const float* Wv   = (const float*)d_in[7];
    const float* bv   = (const float*)d_in[8];
    const float* Wo   = (const float*)d_in[9];
    const float* bo   = (const float*)d_in[10];
    const float* W1   = (const float*)d_in[11];
    const float* b1   = (const float*)d_in[12];
    const float* W2   = (const float*)d_in[13];
    const float* b2   = (const float*)d_in[14];

    float* out = (float*)d_out;

    const size_t SZ = (size_t)M_TOT * DD;   // 4,194,304 floats = 16 MB
    float* qh  = (float*)d_ws;
    float* kh  = qh + SZ;
    float* vh  = kh + SZ;
    float* ctx = vh + SZ;
    // h (post-ReLU FFN hidden) reuses qh's buffer; Wo output uses d_out as scratch.

    const int gemm_grid = M_TOT / 32;   // 1024 blocks

    // QKV projections (Wq/Wk/Wv are (D, H*DK) row-major = 128x128)
    gemm_bias_kernel<<<gemm_grid, 256, 0, stream>>>(vf, Wq, bq, qh, 0);
    gemm_bias_kernel<<<gemm_grid, 256, 0, stream>>>(vf, Wk, bk, kh, 0);
    gemm_bias_kernel<<<gemm_grid, 256, 0, stream>>>(vf, Wv, bv, vh, 0);

    // attention -> ctx
    attn_kernel<<<M_TOT / 2, 256, 0, stream>>>(qh, kh, vh, nbr, vlen, ctx);

    // out = ctx @ Wo + bo   (Wo is (H*DK, D) row-major = 128x128); d_out as scratch
    gemm_bias_kernel<<<gemm_grid, 256, 0, stream>>>(ctx, Wo, bo, out, 0);

    // h = relu(out @ W1 + b1), reuse qh buffer
    gemm_bias_kernel<<<gemm_grid, 256, 0, stream>>>(out, W1, b1, qh, 1);

    // final = h @ W2 + b2 -> d_out
    gemm_bias_kernel<<<gemm_grid, 256, 0, stream>>>(qh, W2, b2, out, 0);
}

// Round 2
// 248.870 us; speedup vs baseline: 1.2971x; 1.2971x over previous
//
#include <hip/hip_runtime.h>
#include <math.h>

#define BB 4
#define NN 8192
#define KNB 16
#define DD 128
#define SS 17            // K+1 (self + neighbors)
#define M_TOT (BB*NN)    // 32768

// ---------------------------------------------------------------------------
// Y[M,128] = act(X[M,128] @ W[128,128] + bias), relu optional.
// 64 rows/block, 256 threads, thread tile 4 rows x 8 cols (cols tx*4..+3 and
// 64+tx*4..+3 so B-reads are contiguous b128, measured conflict-free pattern).
// Xs stride 132 -> A-reads are 2-way (free). W staged in 32-row quarters.
// LDS = 33 KB + 16 KB = 49 KB -> 2 blocks/CU at grid 512.
// ---------------------------------------------------------------------------
#define GR 64
#define XS_STRIDE 132

__global__ __launch_bounds__(256) void gemm_bias_kernel(
    const float* __restrict__ X, const float* __restrict__ W,
    const float* __restrict__ bias, float* __restrict__ Y, int relu)
{
    __shared__ float Xs[GR * XS_STRIDE];   // 33792 B
    __shared__ float Ws[32 * DD];          // 16384 B

    const int tid  = threadIdx.x;
    const int row0 = blockIdx.x * GR;

    // Stage X tile: 64x128 floats = 2048 float4, 8 per thread, coalesced.
    {
        const float4* Xg = (const float4*)(X + (size_t)row0 * DD);
        #pragma unroll
        for (int i = 0; i < 8; ++i) {
            int idx = tid + i * 256;        // 0..2047
            int r   = idx >> 5;
            int c4  = idx & 31;
            float4 val = Xg[idx];
            *((float4*)(Xs + r * XS_STRIDE + c4 * 4)) = val;
        }
    }

    const int tx = tid & 15;    // col group
    const int ty = tid >> 4;    // row group: rows ty*4..ty*4+3

    float acc[4][8];
    #pragma unroll
    for (int i = 0; i < 4; ++i)
        #pragma unroll
        for (int j = 0; j < 8; ++j) acc[i][j] = 0.f;

    for (int kq = 0; kq < 4; ++kq) {
        __syncthreads();   // Xs ready (kq=0) / previous Ws readers done
        {
            const float4* Wg  = (const float4*)(W + kq * 32 * DD);
            float4*       Ws4 = (float4*)Ws;
            #pragma unroll
            for (int i = 0; i < 4; ++i) Ws4[tid + i * 256] = Wg[tid + i * 256];
        }
        __syncthreads();

        #pragma unroll
        for (int d = 0; d < 32; ++d) {
            float4 b0 = ((const float4*)Ws)[d * 32 + tx];        // cols tx*4..+3
            float4 b1 = ((const float4*)Ws)[d * 32 + 16 + tx];   // cols 64+tx*4..+3
            #pragma unroll
            for (int i = 0; i < 4; ++i) {
                float a = Xs[(ty * 4 + i) * XS_STRIDE + kq * 32 + d];
                acc[i][0] = fmaf(a, b0.x, acc[i][0]);
                acc[i][1] = fmaf(a, b0.y, acc[i][1]);
                acc[i][2] = fmaf(a, b0.z, acc[i][2]);
                acc[i][3] = fmaf(a, b0.w, acc[i][3]);
                acc[i][4] = fmaf(a, b1.x, acc[i][4]);
                acc[i][5] = fmaf(a, b1.y, acc[i][5]);
                acc[i][6] = fmaf(a, b1.z, acc[i][6]);
                acc[i][7] = fmaf(a, b1.w, acc[i][7]);
            }
        }
    }

    float4 bb0 = ((const float4*)bias)[tx];
    float4 bb1 = ((const float4*)bias)[16 + tx];
    #pragma unroll
    for (int i = 0; i < 4; ++i) {
        float4 o0, o1;
        o0.x = acc[i][0] + bb0.x;  o0.y = acc[i][1] + bb0.y;
        o0.z = acc[i][2] + bb0.z;  o0.w = acc[i][3] + bb0.w;
        o1.x = acc[i][4] + bb1.x;  o1.y = acc[i][5] + bb1.y;
        o1.z = acc[i][6] + bb1.z;  o1.w = acc[i][7] + bb1.w;
        if (relu) {
            o0.x = fmaxf(o0.x, 0.f); o0.y = fmaxf(o0.y, 0.f);
            o0.z = fmaxf(o0.z, 0.f); o0.w = fmaxf(o0.w, 0.f);
            o1.x = fmaxf(o1.x, 0.f); o1.y = fmaxf(o1.y, 0.f);
            o1.z = fmaxf(o1.z, 0.f); o1.w = fmaxf(o1.w, 0.f);
        }
        float4* Yr = (float4*)(Y + (size_t)(row0 + ty * 4 + i) * DD);
        Yr[tx]      = o0;
        Yr[16 + tx] = o1;
    }
}

// ---------------------------------------------------------------------------
// Attention, fully register-resident: one vertex per 32 lanes (2 per wave),
// lane owns 4 contiguous dims (float4). Head dot = 8-lane shfl_xor reduce.
// Softmax redundantly per lane in registers. No LDS, no __syncthreads.
// ---------------------------------------------------------------------------
__global__ __launch_bounds__(256) void attn_kernel(
    const float* __restrict__ Qh, const float* __restrict__ Kh,
    const float* __restrict__ Vh, const int* __restrict__ nbr,
    const int* __restrict__ vlen, float* __restrict__ Ctx)
{
    const int lane = threadIdx.x & 63;
    const int wv   = threadIdx.x >> 6;   // wave in block: 0..3
    const int pair = lane >> 5;          // vertex within wave: 0/1
    const int c    = lane & 31;          // float4 slot within the 128-dim row
    const int v    = blockIdx.x * 8 + wv * 2 + pair;
    const int b    = v >> 13;            // v / N

    const float4 q4 = ((const float4*)Qh)[(size_t)v * 32 + c];

    int rows[SS];
    rows[0] = v;
    #pragma unroll
    for (int s = 1; s < SS; ++s)
        rows[s] = b * NN + nbr[(size_t)v * KNB + (s - 1)];

    // Pass 1: scores
    float sc[SS];
    #pragma unroll
    for (int s = 0; s < SS; ++s) {
        float4 k4 = ((const float4*)Kh)[(size_t)rows[s] * 32 + c];
        float p = q4.x * k4.x + q4.y * k4.y + q4.z * k4.z + q4.w * k4.w;
        p += __shfl_xor(p, 1, 8);
        p += __shfl_xor(p, 2, 8);
        p += __shfl_xor(p, 4, 8);
        sc[s] = p * 0.17677669529663687f;   // 1/sqrt(32)
    }

    // Masked softmax over s in [0, len], redundantly in every lane.
    const int len = vlen[v];
    float m = sc[0];
    #pragma unroll
    for (int s = 1; s < SS; ++s) m = (s <= len) ? fmaxf(m, sc[s]) : m;
    float sum = 0.f;
    #pragma unroll
    for (int s = 0; s < SS; ++s) {
        float e = (s <= len) ? __expf(sc[s] - m) : 0.f;
        sc[s] = e;
        sum += e;
    }
    const float inv = 1.f / sum;

    // Pass 2: weighted V accumulate
    float4 acc = make_float4(0.f, 0.f, 0.f, 0.f);
    #pragma unroll
    for (int s = 0; s < SS; ++s) {
        float4 v4 = ((const float4*)Vh)[(size_t)rows[s] * 32 + c];
        float w = sc[s] * inv;
        acc.x = fmaf(w, v4.x, acc.x);
        acc.y = fmaf(w, v4.y, acc.y);
        acc.z = fmaf(w, v4.z, acc.z);
        acc.w = fmaf(w, v4.w, acc.w);
    }
    ((float4*)Ctx)[(size_t)v * 32 + c] = acc;
}

// ---------------------------------------------------------------------------
extern "C" void kernel_launch(void* const* d_in, const int* in_sizes, int n_in,
                              void* d_out, int out_size, void* d_ws, size_t ws_size,
                              hipStream_t stream)
{
    const float* vf   = (const float*)d_in[0];
    const int*   nbr  = (const int*)  d_in[1];
    const int*   vlen = (const int*)  d_in[2];
    const float* Wq   = (const float*)d_in[3];
    const float* bq   = (const float*)d_in[4];
    const float* Wk   = (const float*)d_in[5];
    const float* bk   = (const float*)d_in[6];
    const float* Wv   = (const float*)d_in[7];
    const float* bv   = (const float*)d_in[8];
    const float* Wo   = (const float*)d_in[9];
    const float* bo   = (const float*)d_in[10];
    const float* W1   = (const float*)d_in[11];
    const float* b1   = (const float*)d_in[12];
    const float* W2   = (const float*)d_in[13];
    const float* b2   = (const float*)d_in[14];

    float* out = (float*)d_out;

    const size_t SZ = (size_t)M_TOT * DD;   // 16 MB each
    float* qh  = (float*)d_ws;
    float* kh  = qh + SZ;
    float* vh  = kh + SZ;
    float* ctx = vh + SZ;

    const int gemm_grid = M_TOT / GR;   // 512 blocks

    gemm_bias_kernel<<<gemm_grid, 256, 0, stream>>>(vf, Wq, bq, qh, 0);
    gemm_bias_kernel<<<gemm_grid, 256, 0, stream>>>(vf, Wk, bk, kh, 0);
    gemm_bias_kernel<<<gemm_grid, 256, 0, stream>>>(vf, Wv, bv, vh, 0);

    attn_kernel<<<M_TOT / 8, 256, 0, stream>>>(qh, kh, vh, nbr, vlen, ctx);

    gemm_bias_kernel<<<gemm_grid, 256, 0, stream>>>(ctx, Wo, bo, out, 0);
    gemm_bias_kernel<<<gemm_grid, 256, 0, stream>>>(out, W1, b1, qh, 1);
    gemm_bias_kernel<<<gemm_grid, 256, 0, stream>>>(qh, W2, b2, out, 0);
}

// Round 3
// 163.919 us; speedup vs baseline: 1.9693x; 1.5182x over previous
//
#include <hip/hip_runtime.h>
#include <math.h>

#define BB 4
#define NN 8192
#define KNB 16
#define DD 128
#define SS 17            // K+1 (self + neighbors)
#define M_TOT (BB*NN)    // 32768

typedef __attribute__((ext_vector_type(8))) short          bf8;
typedef __attribute__((ext_vector_type(4))) float          f4;
typedef __attribute__((ext_vector_type(4))) unsigned short u16x4;

static __device__ __forceinline__ unsigned short f2bf(float f) {
    unsigned u = __builtin_bit_cast(unsigned, f);
    u += 0x7fffu + ((u >> 16) & 1u);        // round-to-nearest-even
    return (unsigned short)(u >> 16);
}
static __device__ __forceinline__ float bf2f(unsigned short h) {
    return __builtin_bit_cast(float, (unsigned)h << 16);
}

// ---------------------------------------------------------------------------
// fp32 -> bf16 bulk convert (vertex features). 4 elems/thread.
// ---------------------------------------------------------------------------
__global__ __launch_bounds__(256) void cvt_x(const float* __restrict__ in,
                                             unsigned short* __restrict__ out)
{
    int i = blockIdx.x * 256 + threadIdx.x;
    float4 v = ((const float4*)in)[i];
    u16x4 r;
    r[0] = f2bf(v.x); r[1] = f2bf(v.y); r[2] = f2bf(v.z); r[3] = f2bf(v.w);
    *((u16x4*)out + i) = r;
}

// ---------------------------------------------------------------------------
// Transpose+convert all six 128x128 weight matrices to bf16 W^T[n][k].
// 96 blocks: 16 per matrix; thread handles 4 consecutive output elems.
// ---------------------------------------------------------------------------
__global__ __launch_bounds__(256) void cvt_wT(
    const float* __restrict__ Wq, const float* __restrict__ Wk,
    const float* __restrict__ Wv, const float* __restrict__ Wo,
    const float* __restrict__ W1, const float* __restrict__ W2,
    unsigned short* __restrict__ out)
{
    int m = blockIdx.x >> 4;
    const float* src = (m == 0) ? Wq : (m == 1) ? Wk : (m == 2) ? Wv
                     : (m == 3) ? Wo : (m == 4) ? W1 : W2;
    unsigned short* dst = out + m * 16384;
    int o = (blockIdx.x & 15) * 1024 + threadIdx.x * 4;   // output idx [n][k]
    int n = o >> 7, k = o & 127;
    u16x4 r;
    #pragma unroll
    for (int i = 0; i < 4; ++i) r[i] = f2bf(src[(size_t)(k + i) * 128 + n]);
    *(u16x4*)(dst + o) = r;
}

// ---------------------------------------------------------------------------
// Y[M,128] = act(X[M,128] @ W + bias) via bf16 MFMA 16x16x32, fp32 accumulate.
// X row-major bf16; Wt = W^T[n][k] row-major bf16. Block = 4 waves, 64 rows.
// Wave tile 32x64: 2 m-tiles x 4 n-tiles, K=128 fully unrolled (4 k-steps).
// A-frags straight from global (16B/lane, each element read once per block).
// W^T staged in LDS (pad stride 136 elems -> 2-way bank aliasing = free),
// all 16 B-frags loaded to registers before the MFMA loop.
// Fragment maps (m89/m120-verified): A[m=lane&15][k=quad*8+j],
// B[k=quad*8+j][n=lane&15], D[row=quad*4+r][col=lane&15].
// ---------------------------------------------------------------------------
__global__ __launch_bounds__(256) void gemm_mfma(
    const unsigned short* __restrict__ X, const unsigned short* __restrict__ Wt,
    const float* __restrict__ bias, unsigned short* __restrict__ Yb,
    float* __restrict__ Yf, int relu, int f32out)
{
    __shared__ unsigned short Ws[128 * 136];   // 34,816 B

    const int tid = threadIdx.x;

    // Stage W^T: 2048 chunks of 8 elems (16 B), aligned (136*2=272=17*16).
    #pragma unroll
    for (int i = 0; i < 8; ++i) {
        int c = tid + i * 256;
        int n = c >> 4, k8 = c & 15;
        bf8 val = ((const bf8*)Wt)[c];
        *(bf8*)(Ws + n * 136 + k8 * 8) = val;
    }

    const int lane = tid & 63;
    const int wv   = tid >> 6;
    const int wm   = wv >> 1;          // 0..1
    const int wn   = wv & 1;           // 0..1
    const int ln   = lane & 15;
    const int quad = lane >> 4;
    const int row0 = blockIdx.x * 64 + wm * 32;

    __syncthreads();

    // B fragments: 4 n-tiles x 4 k-steps, kept in registers.
    bf8 bfr[4][4];
    #pragma unroll
    for (int t = 0; t < 4; ++t)
        #pragma unroll
        for (int s = 0; s < 4; ++s)
            bfr[t][s] = *(const bf8*)(Ws + (wn * 64 + t * 16 + ln) * 136 + s * 32 + quad * 8);

    f4 acc[2][4] = {};

    #pragma unroll
    for (int s = 0; s < 4; ++s) {
        bf8 a0 = *(const bf8*)(X + (size_t)(row0 + ln)      * DD + s * 32 + quad * 8);
        bf8 a1 = *(const bf8*)(X + (size_t)(row0 + 16 + ln) * DD + s * 32 + quad * 8);
        #pragma unroll
        for (int t = 0; t < 4; ++t) {
            acc[0][t] = __builtin_amdgcn_mfma_f32_16x16x32_bf16(a0, bfr[t][s], acc[0][t], 0, 0, 0);
            acc[1][t] = __builtin_amdgcn_mfma_f32_16x16x32_bf16(a1, bfr[t][s], acc[1][t], 0, 0, 0);
        }
    }

    #pragma unroll
    for (int mt = 0; mt < 2; ++mt) {
        #pragma unroll
        for (int t = 0; t < 4; ++t) {
            const int col  = wn * 64 + t * 16 + ln;
            const float bc = bias[col];
            #pragma unroll
            for (int r = 0; r < 4; ++r) {
                const int row = row0 + mt * 16 + quad * 4 + r;
                float v = acc[mt][t][r] + bc;
                if (relu) v = fmaxf(v, 0.f);
                if (f32out) Yf[(size_t)row * DD + col] = v;
                else        Yb[(size_t)row * DD + col] = f2bf(v);
            }
        }
    }
}

// ---------------------------------------------------------------------------
// Attention, register-resident, bf16 Q/K/V/ctx, fp32 math.
// One vertex per 32 lanes; lane owns 4 dims (8 B loads).
// ---------------------------------------------------------------------------
__global__ __launch_bounds__(256) void attn_kernel(
    const unsigned short* __restrict__ Qh, const unsigned short* __restrict__ Kh,
    const unsigned short* __restrict__ Vh, const int* __restrict__ nbr,
    const int* __restrict__ vlen, unsigned short* __restrict__ Ctx)
{
    const int lane = threadIdx.x & 63;
    const int wv   = threadIdx.x >> 6;
    const int pair = lane >> 5;
    const int c    = lane & 31;
    const int v    = blockIdx.x * 8 + wv * 2 + pair;
    const int b    = v >> 13;

    const u16x4 qu = ((const u16x4*)Qh)[(size_t)v * 32 + c];
    const float q0 = bf2f(qu[0]), q1 = bf2f(qu[1]), q2 = bf2f(qu[2]), q3 = bf2f(qu[3]);

    int rows[SS];
    rows[0] = v;
    #pragma unroll
    for (int s = 1; s < SS; ++s)
        rows[s] = b * NN + nbr[(size_t)v * KNB + (s - 1)];

    float sc[SS];
    #pragma unroll
    for (int s = 0; s < SS; ++s) {
        u16x4 ku = ((const u16x4*)Kh)[(size_t)rows[s] * 32 + c];
        float p = q0 * bf2f(ku[0]) + q1 * bf2f(ku[1]) + q2 * bf2f(ku[2]) + q3 * bf2f(ku[3]);
        p += __shfl_xor(p, 1, 8);
        p += __shfl_xor(p, 2, 8);
        p += __shfl_xor(p, 4, 8);
        sc[s] = p * 0.17677669529663687f;   // 1/sqrt(32)
    }

    const int len = vlen[v];
    float m = sc[0];
    #pragma unroll
    for (int s = 1; s < SS; ++s) m = (s <= len) ? fmaxf(m, sc[s]) : m;
    float sum = 0.f;
    #pragma unroll
    for (int s = 0; s < SS; ++s) {
        float e = (s <= len) ? __expf(sc[s] - m) : 0.f;
        sc[s] = e;
        sum += e;
    }
    const float inv = 1.f / sum;

    float a0 = 0.f, a1 = 0.f, a2 = 0.f, a3 = 0.f;
    #pragma unroll
    for (int s = 0; s < SS; ++s) {
        u16x4 vu = ((const u16x4*)Vh)[(size_t)rows[s] * 32 + c];
        float w = sc[s] * inv;
        a0 = fmaf(w, bf2f(vu[0]), a0);
        a1 = fmaf(w, bf2f(vu[1]), a1);
        a2 = fmaf(w, bf2f(vu[2]), a2);
        a3 = fmaf(w, bf2f(vu[3]), a3);
    }
    u16x4 r;
    r[0] = f2bf(a0); r[1] = f2bf(a1); r[2] = f2bf(a2); r[3] = f2bf(a3);
    ((u16x4*)Ctx)[(size_t)v * 32 + c] = r;
}

// ---------------------------------------------------------------------------
extern "C" void kernel_launch(void* const* d_in, const int* in_sizes, int n_in,
                              void* d_out, int out_size, void* d_ws, size_t ws_size,
                              hipStream_t stream)
{
    const float* vf   = (const float*)d_in[0];
    const int*   nbr  = (const int*)  d_in[1];
    const int*   vlen = (const int*)  d_in[2];
    const float* Wq   = (const float*)d_in[3];
    const float* bq   = (const float*)d_in[4];
    const float* Wk   = (const float*)d_in[5];
    const float* bk   = (const float*)d_in[6];
    const float* Wv   = (const float*)d_in[7];
    const float* bv   = (const float*)d_in[8];
    const float* Wo   = (const float*)d_in[9];
    const float* bo   = (const float*)d_in[10];
    const float* W1   = (const float*)d_in[11];
    const float* b1   = (const float*)d_in[12];
    const float* W2   = (const float*)d_in[13];
    const float* b2   = (const float*)d_in[14];

    float* out = (float*)d_out;

    const size_t SZ = (size_t)M_TOT * DD;        // elems per activation (4.19M)
    unsigned short* Xb   = (unsigned short*)d_ws;        // bf16, 8 MB each
    unsigned short* WtT  = Xb + SZ;                      // 6 x 16384 bf16
    unsigned short* qh   = WtT + 6 * 16384;
    unsigned short* kh   = qh + SZ;
    unsigned short* vh   = kh + SZ;
    unsigned short* ctx  = vh + SZ;
    unsigned short* obuf = ctx + SZ;
    unsigned short* hbuf = obuf + SZ;

    unsigned short* WqT = WtT;
    unsigned short* WkT = WtT + 16384;
    unsigned short* WvT = WtT + 2 * 16384;
    unsigned short* WoT = WtT + 3 * 16384;
    unsigned short* W1T = WtT + 4 * 16384;
    unsigned short* W2T = WtT + 5 * 16384;

    cvt_x <<<SZ / 1024, 256, 0, stream>>>(vf, Xb);
    cvt_wT<<<96,        256, 0, stream>>>(Wq, Wk, Wv, Wo, W1, W2, WtT);

    const int gg = M_TOT / 64;   // 512 blocks

    gemm_mfma<<<gg, 256, 0, stream>>>(Xb, WqT, bq, qh, nullptr, 0, 0);
    gemm_mfma<<<gg, 256, 0, stream>>>(Xb, WkT, bk, kh, nullptr, 0, 0);
    gemm_mfma<<<gg, 256, 0, stream>>>(Xb, WvT, bv, vh, nullptr, 0, 0);

    attn_kernel<<<M_TOT / 8, 256, 0, stream>>>(qh, kh, vh, nbr, vlen, ctx);

    gemm_mfma<<<gg, 256, 0, stream>>>(ctx,  WoT, bo, obuf, nullptr, 0, 0);
    gemm_mfma<<<gg, 256, 0, stream>>>(obuf, W1T, b1, hbuf, nullptr, 1, 0);
    gemm_mfma<<<gg, 256, 0, stream>>>(hbuf, W2T, b2, nullptr, out,  0, 1);
}